// Round 1
// baseline (316.786 us; speedup 1.0000x reference)
//
#include <hip/hip_runtime.h>
#include <hip/hip_bf16.h>

#define BATCH 128
#define DMEM 64
#define NHEAD 16
#define NMEM 4096
#define DMODEL 1024

typedef __bf16 v8bf __attribute__((ext_vector_type(8)));
typedef __bf16 v2bf __attribute__((ext_vector_type(2)));
typedef float v4f __attribute__((ext_vector_type(4)));

// ---------------------------------------------------------------------------
// Kernel 1 & 3: C[M=128][N=1024] = A[128][1024] @ W[1024][1024]^T + bias
// 32x32 tiles, K-chunks of 32, 256 threads, 2x2 micro-tile (rows rp/rp+16,
// cols cp/cp+16 so LDS reads are broadcast / 2-way conflict-free).
// ---------------------------------------------------------------------------
__global__ __launch_bounds__(256) void gemm_bt(const float* __restrict__ A,
                                               const float* __restrict__ W,
                                               const float* __restrict__ bias,
                                               float* __restrict__ C,
                                               int relu) {
    __shared__ float As[32][36];
    __shared__ float Ws[32][36];
    const int t = threadIdx.x;
    const int m0 = blockIdx.x * 32;
    const int n0 = blockIdx.y * 32;
    const int lrow = t >> 3;        // 0..31
    const int lc4 = (t & 7) * 4;    // 0,4,...,28
    const int rp = t >> 4;          // 0..15
    const int cp = t & 15;          // 0..15

    float acc00 = 0.f, acc01 = 0.f, acc10 = 0.f, acc11 = 0.f;

    for (int kc = 0; kc < DMODEL; kc += 32) {
        v4f av = *(const v4f*)&A[(size_t)(m0 + lrow) * DMODEL + kc + lc4];
        v4f wv = *(const v4f*)&W[(size_t)(n0 + lrow) * DMODEL + kc + lc4];
        __syncthreads();
        *(v4f*)&As[lrow][lc4] = av;
        *(v4f*)&Ws[lrow][lc4] = wv;
        __syncthreads();
#pragma unroll
        for (int kk = 0; kk < 32; kk += 4) {
            v4f a0 = *(v4f*)&As[rp][kk];
            v4f a1 = *(v4f*)&As[rp + 16][kk];
            v4f b0 = *(v4f*)&Ws[cp][kk];
            v4f b1 = *(v4f*)&Ws[cp + 16][kk];
#pragma unroll
            for (int q = 0; q < 4; ++q) {
                acc00 = fmaf(a0[q], b0[q], acc00);
                acc01 = fmaf(a0[q], b1[q], acc01);
                acc10 = fmaf(a1[q], b0[q], acc10);
                acc11 = fmaf(a1[q], b1[q], acc11);
            }
        }
    }
    float bv0 = bias[n0 + cp];
    float bv1 = bias[n0 + cp + 16];
    float o00 = acc00 + bv0, o01 = acc01 + bv1;
    float o10 = acc10 + bv0, o11 = acc11 + bv1;
    if (relu) {
        o00 = fmaxf(o00, 0.f); o01 = fmaxf(o01, 0.f);
        o10 = fmaxf(o10, 0.f); o11 = fmaxf(o11, 0.f);
    }
    C[(size_t)(m0 + rp) * 1024 + n0 + cp] = o00;
    C[(size_t)(m0 + rp) * 1024 + n0 + cp + 16] = o01;
    C[(size_t)(m0 + rp + 16) * 1024 + n0 + cp] = o10;
    C[(size_t)(m0 + rp + 16) * 1024 + n0 + cp + 16] = o11;
}

// ---------------------------------------------------------------------------
// Kernel 2a: per (batch b, split s) block computes partial
//   matrix[d][e] = sum_n relu(m[n][d]+a[n][d]) * m[n][e]   (64x64)
//   norm[d]      = sum_n relu(m[n][d]+a[n][d])
// over slots [s*slots_per, (s+1)*slots_per). bf16 MFMA 16x16x32.
// LDS tiles are dim-major [64][LDS_STRIDE] so A/B frags are contiguous 16B.
// ---------------------------------------------------------------------------
#define LDS_STRIDE 40  // bf16 elems; 80B rows -> 16B aligned, 2-way banks

__global__ __launch_bounds__(256) void stage1(const float* __restrict__ mem,
                                              const float* __restrict__ addr,
                                              float* __restrict__ pmat,
                                              float* __restrict__ pnorm,
                                              int S) {
    __shared__ __bf16 k_lds[64 * LDS_STRIDE];
    __shared__ __bf16 m_lds[64 * LDS_STRIDE];
    __shared__ float norm_s[16 * 64];

    const int t = threadIdx.x;
    const int bid = blockIdx.x;
    const int b = bid & (BATCH - 1);
    const int s = bid >> 7;
    const int slots_per = NMEM / S;
    const int chunks = slots_per >> 5;  // 32 slots per chunk

    // staging role: thread covers d [4u,4u+4) x slots {2v, 2v+1} of each chunk
    const int u = t & 15;
    const int v = t >> 4;
    const int d0 = u * 4;

    // mfma role
    const int wave = t >> 6;
    const int l = t & 63;
    const int quad = l >> 4;
    const int lo = l & 15;

    const size_t mem_base = ((size_t)b * NMEM + (size_t)s * slots_per) * DMEM;
    const size_t addr_base = (size_t)s * slots_per * DMEM;

    v4f acc[4];
#pragma unroll
    for (int j = 0; j < 4; ++j) acc[j] = (v4f){0.f, 0.f, 0.f, 0.f};
    float nacc[4] = {0.f, 0.f, 0.f, 0.f};

    for (int c = 0; c < chunks; ++c) {
        const size_t coff = (size_t)c * 32 * DMEM;
        const size_t so = (size_t)(2 * v) * DMEM + d0;
        v4f m0 = *(const v4f*)&mem[mem_base + coff + so];
        v4f m1 = *(const v4f*)&mem[mem_base + coff + so + DMEM];
        v4f a0 = *(const v4f*)&addr[addr_base + coff + so];
        v4f a1 = *(const v4f*)&addr[addr_base + coff + so + DMEM];

        __syncthreads();  // previous chunk's frag reads done before overwrite
#pragma unroll
        for (int i = 0; i < 4; ++i) {
            float kf0 = fmaxf(m0[i] + a0[i], 0.f);
            float kf1 = fmaxf(m1[i] + a1[i], 0.f);
            nacc[i] += kf0 + kf1;
            v2bf kp; kp[0] = (__bf16)kf0; kp[1] = (__bf16)kf1;
            v2bf mp; mp[0] = (__bf16)m0[i]; mp[1] = (__bf16)m1[i];
            *(v2bf*)&k_lds[(d0 + i) * LDS_STRIDE + 2 * v] = kp;
            *(v2bf*)&m_lds[(d0 + i) * LDS_STRIDE + 2 * v] = mp;
        }
        __syncthreads();

        // A[d][kk] = k[slot=kk][d]  -> k_lds row (16*wave+lo), col quad*8..+7
        v8bf af = *(v8bf*)&k_lds[(16 * wave + lo) * LDS_STRIDE + quad * 8];
#pragma unroll
        for (int j = 0; j < 4; ++j) {
            v8bf bf = *(v8bf*)&m_lds[(16 * j + lo) * LDS_STRIDE + quad * 8];
            acc[j] = __builtin_amdgcn_mfma_f32_16x16x32_bf16(af, bf, acc[j], 0, 0, 0);
        }
    }

    // write 64x64 partial: C/D layout col=lane&15, row=quad*4+reg
#pragma unroll
    for (int j = 0; j < 4; ++j) {
#pragma unroll
        for (int r = 0; r < 4; ++r) {
            int d = 16 * wave + quad * 4 + r;
            int e = 16 * j + lo;
            pmat[(size_t)bid * 4096 + d * 64 + e] = acc[j][r];
        }
    }

    // normalizer: reduce 16 thread-groups
#pragma unroll
    for (int i = 0; i < 4; ++i) norm_s[v * 64 + d0 + i] = nacc[i];
    __syncthreads();
    if (t < 64) {
        float sacc = 0.f;
#pragma unroll
        for (int g = 0; g < 16; ++g) sacc += norm_s[g * 64 + t];
        pnorm[(size_t)bid * 64 + t] = sacc;
    }
}

// ---------------------------------------------------------------------------
// Kernel 2b: per batch, sum S partials -> matrix/normalizer; then
// attn[h][e] = (sum_d qa[h][d]*matrix[d][e]) / (sum_d qa[h][d]*norm[d] + 1e-5)
// ---------------------------------------------------------------------------
__global__ __launch_bounds__(256) void stage2(const float* __restrict__ pmat,
                                              const float* __restrict__ pnorm,
                                              const float* __restrict__ qa,
                                              float* __restrict__ attn,
                                              int S) {
    __shared__ float mat_s[4096];
    __shared__ float qa_s[1024];
    __shared__ float nrm_s[64];
    const int t = threadIdx.x;
    const int b = blockIdx.x;

#pragma unroll
    for (int i = 0; i < 16; ++i) {
        int idx = t + 256 * i;
        float ssum = 0.f;
        for (int s = 0; s < S; ++s)
            ssum += pmat[((size_t)s * BATCH + b) * 4096 + idx];
        mat_s[idx] = ssum;
    }
    if (t < 64) {
        float ssum = 0.f;
        for (int s = 0; s < S; ++s)
            ssum += pnorm[((size_t)s * BATCH + b) * 64 + t];
        nrm_s[t] = ssum;
    }
#pragma unroll
    for (int i = 0; i < 4; ++i)
        qa_s[t + 256 * i] = qa[(size_t)b * 1024 + t + 256 * i];
    __syncthreads();

    const int e = t & 63;
    const int hq = t >> 6;
#pragma unroll
    for (int i = 0; i < 4; ++i) {
        int h = hq + 4 * i;
        float num = 0.f, den = 0.f;
#pragma unroll 8
        for (int d = 0; d < 64; ++d) {
            float q = qa_s[h * 64 + d];
            num = fmaf(q, mat_s[d * 64 + e], num);
            den = fmaf(q, nrm_s[d], den);
        }
        attn[(size_t)b * 1024 + h * 64 + e] = num / (den + 1e-5f);
    }
}

// ---------------------------------------------------------------------------
extern "C" void kernel_launch(void* const* d_in, const int* in_sizes, int n_in,
                              void* d_out, int out_size, void* d_ws, size_t ws_size,
                              hipStream_t stream) {
    const float* query     = (const float*)d_in[0];
    const float* addresses = (const float*)d_in[1];
    const float* memories  = (const float*)d_in[2];
    const float* Wq        = (const float*)d_in[3];
    const float* bq        = (const float*)d_in[4];
    const float* Wm        = (const float*)d_in[5];
    const float* bm        = (const float*)d_in[6];
    float* out = (float*)d_out;
    float* ws = (float*)d_ws;

    int S = 8;
    while (S > 1) {
        size_t need = ((size_t)262144 + (size_t)S * (8192 + 524288)) * sizeof(float);
        if (need <= ws_size) break;
        S >>= 1;
    }

    float* qa_ws   = ws;                       // 131072 floats
    float* attn_ws = ws + 131072;              // 131072 floats
    float* pnorm   = ws + 262144;              // S*128*64 floats
    float* pmat    = pnorm + (size_t)S * 8192; // S*128*4096 floats

    gemm_bt<<<dim3(4, 32), 256, 0, stream>>>(query, Wq, bq, qa_ws, 1);
    stage1<<<dim3(BATCH * S), 256, 0, stream>>>(memories, addresses, pmat, pnorm, S);
    stage2<<<dim3(BATCH), 256, 0, stream>>>(pmat, pnorm, qa_ws, attn_ws, S);
    gemm_bt<<<dim3(4, 32), 256, 0, stream>>>(attn_ws, Wm, bm, out, 0);
}

// Round 2
// 260.270 us; speedup vs baseline: 1.2171x; 1.2171x over previous
//
#include <hip/hip_runtime.h>
#include <hip/hip_bf16.h>

#define BATCH 128
#define DMEM 64
#define NHEAD 16
#define NMEM 4096
#define DMODEL 1024

typedef __bf16 v8bf __attribute__((ext_vector_type(8)));
typedef __bf16 v2bf __attribute__((ext_vector_type(2)));
typedef float v4f __attribute__((ext_vector_type(4)));

// ---------------------------------------------------------------------------
// Shared GEMM body: C[m0:m0+32][n0:n0+32] += A[.][k0:k0+32*nchunks] @ W^T
// (atomicAdd accumulate; optional bias added by this block). 256 threads,
// 2x2 micro-tile, register prefetch of the next K-chunk during compute.
// smem must hold 2*32*36 floats.
// ---------------------------------------------------------------------------
__device__ __forceinline__ void gemm_sk(const float* __restrict__ A,
                                        const float* __restrict__ W,
                                        const float* __restrict__ bias,
                                        float* __restrict__ C,
                                        int m0, int n0, int k0, int nchunks,
                                        float* smem) {
    float(*As)[36] = (float(*)[36])smem;
    float(*Ws)[36] = (float(*)[36])(smem + 32 * 36);
    const int t = threadIdx.x;
    const int lrow = t >> 3;      // 0..31
    const int lc4 = (t & 7) * 4;  // 0..28
    const int rp = t >> 4;        // 0..15
    const int cp = t & 15;        // 0..15

    float acc00 = 0.f, acc01 = 0.f, acc10 = 0.f, acc11 = 0.f;

    v4f av = *(const v4f*)&A[(size_t)(m0 + lrow) * DMODEL + k0 + lc4];
    v4f wv = *(const v4f*)&W[(size_t)(n0 + lrow) * DMODEL + k0 + lc4];

    for (int c = 0; c < nchunks; ++c) {
        __syncthreads();
        *(v4f*)&As[lrow][lc4] = av;
        *(v4f*)&Ws[lrow][lc4] = wv;
        __syncthreads();
        if (c + 1 < nchunks) {
            const int kc = k0 + (c + 1) * 32;
            av = *(const v4f*)&A[(size_t)(m0 + lrow) * DMODEL + kc + lc4];
            wv = *(const v4f*)&W[(size_t)(n0 + lrow) * DMODEL + kc + lc4];
        }
#pragma unroll
        for (int kk = 0; kk < 32; kk += 4) {
            v4f a0 = *(v4f*)&As[rp][kk];
            v4f a1 = *(v4f*)&As[rp + 16][kk];
            v4f b0 = *(v4f*)&Ws[cp][kk];
            v4f b1 = *(v4f*)&Ws[cp + 16][kk];
#pragma unroll
            for (int q = 0; q < 4; ++q) {
                acc00 = fmaf(a0[q], b0[q], acc00);
                acc01 = fmaf(a0[q], b1[q], acc01);
                acc10 = fmaf(a1[q], b0[q], acc10);
                acc11 = fmaf(a1[q], b1[q], acc11);
            }
        }
    }
    float bv0 = 0.f, bv1 = 0.f;
    if (bias) { bv0 = bias[n0 + cp]; bv1 = bias[n0 + cp + 16]; }
    atomicAdd(&C[(size_t)(m0 + rp) * 1024 + n0 + cp], acc00 + bv0);
    atomicAdd(&C[(size_t)(m0 + rp) * 1024 + n0 + cp + 16], acc01 + bv1);
    atomicAdd(&C[(size_t)(m0 + rp + 16) * 1024 + n0 + cp], acc10 + bv0);
    atomicAdd(&C[(size_t)(m0 + rp + 16) * 1024 + n0 + cp + 16], acc11 + bv1);
}

// ---------------------------------------------------------------------------
// K1: blocks [0, B*S)      -> stage1 partials (bf16 MFMA, pipelined)
//     blocks [B*S, +1024)  -> q-projection split-K partials into qa_ws
// Runs the latency-bound GEMM concurrently with the HBM-bound stage1.
// ---------------------------------------------------------------------------
#define LDS_STRIDE 40  // bf16 elems; 80B rows, 16B-aligned b128 frag reads

__global__ __launch_bounds__(256) void k1(const float* __restrict__ mem,
                                          const float* __restrict__ addr,
                                          float* __restrict__ pmat,
                                          float* __restrict__ pnorm,
                                          const float* __restrict__ query,
                                          const float* __restrict__ Wq,
                                          float* __restrict__ qa_ws,
                                          int S) {
    __shared__ __align__(16) char smem_raw[14336];
    const int bid = blockIdx.x;
    const int nst = BATCH * S;

    if (bid >= nst) {
        const int b2 = bid - nst;            // 0..1023
        const int m0 = (b2 & 3) * 32;
        const int n0 = ((b2 >> 2) & 31) * 32;
        const int ks = b2 >> 7;              // 0..7
        gemm_sk(query, Wq, nullptr, qa_ws, m0, n0, ks * 128, 4, (float*)smem_raw);
        return;
    }

    __bf16* k_lds = (__bf16*)smem_raw;                 // 5120 B
    __bf16* m_lds = (__bf16*)(smem_raw + 5120);        // 5120 B
    float* norm_s = (float*)(smem_raw + 10240);        // 4096 B

    const int t = threadIdx.x;
    const int b = bid & (BATCH - 1);
    const int s = bid >> 7;
    const int slots_per = NMEM / S;
    const int chunks = slots_per >> 5;  // 32 slots per chunk

    const int u = t & 15;
    const int v = t >> 4;
    const int d0 = u * 4;

    const int wave = t >> 6;
    const int l = t & 63;
    const int quad = l >> 4;
    const int lo = l & 15;

    const size_t mem_base = ((size_t)b * NMEM + (size_t)s * slots_per) * DMEM;
    const size_t addr_base = (size_t)s * slots_per * DMEM;
    const size_t so = (size_t)(2 * v) * DMEM + d0;

    v4f acc[4];
#pragma unroll
    for (int j = 0; j < 4; ++j) acc[j] = (v4f){0.f, 0.f, 0.f, 0.f};
    float nacc[4] = {0.f, 0.f, 0.f, 0.f};

    v4f m0v = *(const v4f*)&mem[mem_base + so];
    v4f m1v = *(const v4f*)&mem[mem_base + so + DMEM];
    v4f a0v = *(const v4f*)&addr[addr_base + so];
    v4f a1v = *(const v4f*)&addr[addr_base + so + DMEM];

    for (int c = 0; c < chunks; ++c) {
        __syncthreads();  // prior chunk's frag reads complete
#pragma unroll
        for (int i = 0; i < 4; ++i) {
            float kf0 = fmaxf(m0v[i] + a0v[i], 0.f);
            float kf1 = fmaxf(m1v[i] + a1v[i], 0.f);
            nacc[i] += kf0 + kf1;
            v2bf kp; kp[0] = (__bf16)kf0; kp[1] = (__bf16)kf1;
            v2bf mp; mp[0] = (__bf16)m0v[i]; mp[1] = (__bf16)m1v[i];
            *(v2bf*)&k_lds[(d0 + i) * LDS_STRIDE + 2 * v] = kp;
            *(v2bf*)&m_lds[(d0 + i) * LDS_STRIDE + 2 * v] = mp;
        }
        __syncthreads();

        if (c + 1 < chunks) {  // prefetch next chunk; latency hides under MFMA
            const size_t coff = (size_t)(c + 1) * 32 * DMEM;
            m0v = *(const v4f*)&mem[mem_base + coff + so];
            m1v = *(const v4f*)&mem[mem_base + coff + so + DMEM];
            a0v = *(const v4f*)&addr[addr_base + coff + so];
            a1v = *(const v4f*)&addr[addr_base + coff + so + DMEM];
        }

        v8bf af = *(v8bf*)&k_lds[(16 * wave + lo) * LDS_STRIDE + quad * 8];
#pragma unroll
        for (int j = 0; j < 4; ++j) {
            v8bf bf = *(v8bf*)&m_lds[(16 * j + lo) * LDS_STRIDE + quad * 8];
            acc[j] = __builtin_amdgcn_mfma_f32_16x16x32_bf16(af, bf, acc[j], 0, 0, 0);
        }
    }

    // C/D layout: col = lane&15, row = quad*4 + reg
#pragma unroll
    for (int j = 0; j < 4; ++j) {
#pragma unroll
        for (int r = 0; r < 4; ++r) {
            int d = 16 * wave + quad * 4 + r;
            int e = 16 * j + lo;
            pmat[(size_t)bid * 4096 + d * 64 + e] = acc[j][r];
        }
    }

#pragma unroll
    for (int i = 0; i < 4; ++i) norm_s[v * 64 + d0 + i] = nacc[i];
    __syncthreads();
    if (t < 64) {
        float sacc = 0.f;
#pragma unroll
        for (int g = 0; g < 16; ++g) sacc += norm_s[g * 64 + t];
        pnorm[(size_t)bid * 64 + t] = sacc;
    }
}

// ---------------------------------------------------------------------------
// stage2: per batch, reduce S partials, finish qa = relu(q_raw + bq), then
// attn[h][e] = (qa[h]·matrix[:,e]) / (qa[h]·norm + 1e-5)
// ---------------------------------------------------------------------------
__global__ __launch_bounds__(256) void stage2(const float* __restrict__ pmat,
                                              const float* __restrict__ pnorm,
                                              const float* __restrict__ qa_raw,
                                              const float* __restrict__ bq,
                                              float* __restrict__ attn,
                                              int S) {
    __shared__ float mat_s[4096];
    __shared__ float qa_s[1024];
    __shared__ float nrm_s[64];
    const int t = threadIdx.x;
    const int b = blockIdx.x;

#pragma unroll
    for (int i = 0; i < 4; ++i) {
        const int vi = (t + 256 * i) * 4;
        v4f ssum = (v4f){0.f, 0.f, 0.f, 0.f};
        for (int s = 0; s < S; ++s) {
            v4f p = *(const v4f*)&pmat[((size_t)s * BATCH + b) * 4096 + vi];
            ssum += p;
        }
        *(v4f*)&mat_s[vi] = ssum;
    }
    if (t < 64) {
        float ssum = 0.f;
        for (int s = 0; s < S; ++s)
            ssum += pnorm[((size_t)s * BATCH + b) * 64 + t];
        nrm_s[t] = ssum;
    }
#pragma unroll
    for (int i = 0; i < 4; ++i) {
        const int idx = t + 256 * i;
        qa_s[idx] = fmaxf(qa_raw[(size_t)b * 1024 + idx] + bq[idx], 0.f);
    }
    __syncthreads();

    const int e = t & 63;
    const int hq = t >> 6;
#pragma unroll
    for (int i = 0; i < 4; ++i) {
        const int h = hq + 4 * i;
        float num = 0.f, den = 0.f;
#pragma unroll 8
        for (int d = 0; d < 64; ++d) {
            float q = qa_s[h * 64 + d];
            num = fmaf(q, mat_s[d * 64 + e], num);
            den = fmaf(q, nrm_s[d], den);
        }
        attn[(size_t)b * 1024 + h * 64 + e] = num / (den + 1e-5f);
    }
}

// ---------------------------------------------------------------------------
// K3: final GEMM, split-K over blockIdx.z, atomicAdd into zeroed d_out.
// ---------------------------------------------------------------------------
__global__ __launch_bounds__(256) void gemm_sk_kernel(const float* __restrict__ A,
                                                      const float* __restrict__ W,
                                                      const float* __restrict__ bias,
                                                      float* __restrict__ C) {
    __shared__ __align__(16) float smem[2 * 32 * 36];
    const int m0 = blockIdx.x * 32;
    const int n0 = blockIdx.y * 32;
    const int ks = blockIdx.z;
    gemm_sk(A, W, ks == 0 ? bias : nullptr, C, m0, n0, ks * 128, 4, smem);
}

// ---------------------------------------------------------------------------
extern "C" void kernel_launch(void* const* d_in, const int* in_sizes, int n_in,
                              void* d_out, int out_size, void* d_ws, size_t ws_size,
                              hipStream_t stream) {
    const float* query     = (const float*)d_in[0];
    const float* addresses = (const float*)d_in[1];
    const float* memories  = (const float*)d_in[2];
    const float* Wq        = (const float*)d_in[3];
    const float* bq        = (const float*)d_in[4];
    const float* Wm        = (const float*)d_in[5];
    const float* bm        = (const float*)d_in[6];
    float* out = (float*)d_out;
    float* ws = (float*)d_ws;

    int S = 8;
    while (S > 1) {
        size_t need = ((size_t)262144 + (size_t)S * (8192 + 524288)) * sizeof(float);
        if (need <= ws_size) break;
        S >>= 1;
    }

    float* qa_ws   = ws;                       // 131072 floats (raw partials)
    float* attn_ws = ws + 131072;              // 131072 floats
    float* pnorm   = ws + 262144;              // S*128*64 floats
    float* pmat    = pnorm + (size_t)S * 8192; // S*128*4096 floats

    hipMemsetAsync(qa_ws, 0, 131072 * sizeof(float), stream);
    hipMemsetAsync(out, 0, (size_t)out_size * sizeof(float), stream);

    k1<<<dim3(BATCH * S + 1024), 256, 0, stream>>>(memories, addresses, pmat,
                                                   pnorm, query, Wq, qa_ws, S);
    stage2<<<dim3(BATCH), 256, 0, stream>>>(pmat, pnorm, qa_ws, bq, attn_ws, S);
    gemm_sk_kernel<<<dim3(4, 32, 8), 256, 0, stream>>>(attn_ws, Wm, bm, out);
}